// Round 3
// baseline (995.166 us; speedup 1.0000x reference)
//
#include <hip/hip_runtime.h>
#include <hip/hip_bf16.h>

#define E_ 8
#define D_ 1024
#define F_ 4096
#define G_ 2048

typedef __attribute__((ext_vector_type(8))) short bf16x8;
typedef __attribute__((ext_vector_type(4))) float f32x4;
typedef __attribute__((ext_vector_type(8))) unsigned short u16x8;
typedef unsigned short u16;
typedef unsigned int u32;

// round-to-nearest-even fp32 -> bf16 (branchless)
__device__ __forceinline__ u16 f2bf(float f) {
  u32 u = __float_as_uint(f);
  u = (u + 0x7fffu + ((u >> 16) & 1u)) >> 16;
  return (u16)u;
}

// async global->LDS, 16B per lane; LDS dest = base + lane*16 (wave-uniform base)
__device__ __forceinline__ void gld_lds16(const void* g, void* l) {
  __builtin_amdgcn_global_load_lds(
      (const __attribute__((address_space(1))) u32*)g,
      (__attribute__((address_space(3))) u32*)l, 16, 0, 0);
}

// ---------------- elementwise fp32 -> bf16 ----------------
__global__ __launch_bounds__(256) void k_cvt(const float* __restrict__ in,
                                             u16* __restrict__ out, int n8) {
  int i = blockIdx.x * 256 + threadIdx.x;
  if (i >= n8) return;
  const float4* p = (const float4*)in + (size_t)i * 2;
  float4 a = p[0], b = p[1];
  u16x8 o;
  o[0] = f2bf(a.x); o[1] = f2bf(a.y); o[2] = f2bf(a.z); o[3] = f2bf(a.w);
  o[4] = f2bf(b.x); o[5] = f2bf(b.y); o[6] = f2bf(b.z); o[7] = f2bf(b.w);
  *(u16x8*)(out + (size_t)i * 8) = o;
}

// ---- transpose+convert v3: in [B][R][C] fp32 -> out [B][C][R] bf16 ----
// 64x64 tile. Phase 1: 4x float4 coalesced loads -> register 4x4 transpose ->
// 4x ds_write_b64 into [c][r] LDS (stride 68 elems = 136B, 8B-aligned).
// Bank check (instr i): dword bank = (8*(cq&3) + 2*rb + 2i) -> 32 banks x 4
// accesses = floor -> conflict-free. Phase 2: 2x 8B reads (banks 2cc+4rq,
// balanced) -> u16x8 coalesced 16B stores (8 lanes = 128B segments).
__global__ __launch_bounds__(256) void k_tcvt(const float* __restrict__ in,
                                              u16* __restrict__ out, int R, int C) {
  __shared__ __align__(16) u16 Tt[64 * 68];
  size_t base = (size_t)blockIdx.z * (size_t)R * (size_t)C;
  in += base; out += base;
  const int c0 = blockIdx.x * 64, r0 = blockIdx.y * 64;
  const int tid = threadIdx.x;
  {
    const int cq = tid & 15, rb = tid >> 4;  // c-quad (16), r-quad (16)
    float4 v[4];
    const float* ip = in + (size_t)(r0 + rb * 4) * C + c0 + cq * 4;
#pragma unroll
    for (int rr = 0; rr < 4; rr++) v[rr] = *(const float4*)(ip + (size_t)rr * C);
#pragma unroll
    for (int i = 0; i < 4; i++) {
      ushort4 pk;
      pk.x = f2bf((&v[0].x)[i]); pk.y = f2bf((&v[1].x)[i]);
      pk.z = f2bf((&v[2].x)[i]); pk.w = f2bf((&v[3].x)[i]);
      *(ushort4*)(Tt + (cq * 4 + i) * 68 + rb * 4) = pk;
    }
  }
  __syncthreads();
  {
    const int rq = tid & 7, cc = tid >> 3;  // r-octet (8), c (32)
#pragma unroll
    for (int it = 0; it < 2; it++) {
      const int c = cc + 32 * it;
      ushort4 a = *(const ushort4*)(Tt + c * 68 + rq * 8);
      ushort4 b = *(const ushort4*)(Tt + c * 68 + rq * 8 + 4);
      u16x8 o;
      o[0] = a.x; o[1] = a.y; o[2] = a.z; o[3] = a.w;
      o[4] = b.x; o[5] = b.y; o[6] = b.z; o[7] = b.w;
      *(u16x8*)(out + (size_t)(c0 + c) * R + r0 + rq * 8) = o;
    }
  }
}

// ---------------- fused GEMM1+GEMM2 + SwiGLU ----------------
// middle = X@W1, gate = X@W2, H = silu(middle)*gate   (per expert)
// X: [G,D] bf16; W1t/W2t: [F,D] bf16 (k-contig); H: [G,F] bf16
// tile BM=128 BN=64 BK=32, 4 waves 2x2. LDS XOR-swizzle (round-2, verified
// conflict-free). 1D grid + XCD patch swizzle: patch = 4bm x 8bn (A 1MB +
// B 2MB = 3MB <= 4MB XCD-L2); patch -> XCD via (linear_id & 7).
__global__ __launch_bounds__(256) void k_mlp1(const u16* __restrict__ X,
                                              const u16* __restrict__ W1t,
                                              const u16* __restrict__ W2t,
                                              u16* __restrict__ H) {
  __shared__ __align__(16) u16 As[128 * 32];   // 8KB
  __shared__ __align__(16) u16 B1s[64 * 32];   // 4KB
  __shared__ __align__(16) u16 B2s[64 * 32];   // 4KB
  // decode: 8192 blocks -> (e, bm-tile 0..15, bn-tile 0..63), patches on XCDs
  const int l = blockIdx.x;
  const int xcd = l & 7, s = l >> 3;
  const int wp = s & 31, pl = s >> 5;
  const int pg = pl * 8 + xcd;          // 0..255
  const int e = pg >> 5, pe = pg & 31;  // 32 patches/expert
  const int bm = ((pe >> 3) * 4 + (wp >> 3)) * 128;
  const int bn = ((pe & 7) * 8 + (wp & 7)) * 64;

  const u16* A  = X   + (size_t)e * G_ * D_;
  const u16* B1 = W1t + (size_t)e * F_ * D_;
  const u16* B2 = W2t + (size_t)e * F_ * D_;
  u16* Hp = H + (size_t)e * G_ * F_;
  const int tid = threadIdx.x, wave = tid >> 6, lane = tid & 63;
  const int wm = (wave >> 1) * 64, wn = (wave & 1) * 32;
  const int quad = lane >> 4, l16 = lane & 15;

  const int ea0 = wave * 512 + lane * 8;
  const int ra0 = ea0 >> 5, ra1 = ra0 + 64;
  const int qs0 = (ea0 >> 3) & 3;
  const int ca0 = (qs0 ^ ((ra0 >> 1) & 3)) << 3;  // swizzled global col offset
  const int fco = ((quad ^ ((l16 >> 1) & 3)) << 3);

  f32x4 acc1[4][2], acc2[4][2];
#pragma unroll
  for (int i = 0; i < 4; i++)
#pragma unroll
    for (int j = 0; j < 2; j++) {
      acc1[i][j] = f32x4{0.f, 0.f, 0.f, 0.f};
      acc2[i][j] = f32x4{0.f, 0.f, 0.f, 0.f};
    }

  for (int k0 = 0; k0 < D_; k0 += 32) {
    gld_lds16(A  + (size_t)(bm + ra0) * D_ + k0 + ca0, (char*)As  + wave * 1024);
    gld_lds16(A  + (size_t)(bm + ra1) * D_ + k0 + ca0, (char*)As  + (wave + 4) * 1024);
    gld_lds16(B1 + (size_t)(bn + ra0) * D_ + k0 + ca0, (char*)B1s + wave * 1024);
    gld_lds16(B2 + (size_t)(bn + ra0) * D_ + k0 + ca0, (char*)B2s + wave * 1024);
    __syncthreads();
    bf16x8 af[4], b1f[2], b2f[2];
#pragma unroll
    for (int i = 0; i < 4; i++)
      af[i] = *(const bf16x8*)(As + (wm + i * 16 + l16) * 32 + fco);
#pragma unroll
    for (int j = 0; j < 2; j++) {
      b1f[j] = *(const bf16x8*)(B1s + (wn + j * 16 + l16) * 32 + fco);
      b2f[j] = *(const bf16x8*)(B2s + (wn + j * 16 + l16) * 32 + fco);
    }
#pragma unroll
    for (int i = 0; i < 4; i++)
#pragma unroll
      for (int j = 0; j < 2; j++) {
        acc1[i][j] = __builtin_amdgcn_mfma_f32_16x16x32_bf16(af[i], b1f[j], acc1[i][j], 0, 0, 0);
        acc2[i][j] = __builtin_amdgcn_mfma_f32_16x16x32_bf16(af[i], b2f[j], acc2[i][j], 0, 0, 0);
      }
    __syncthreads();
  }
#pragma unroll
  for (int i = 0; i < 4; i++)
#pragma unroll
    for (int j = 0; j < 2; j++)
#pragma unroll
      for (int r = 0; r < 4; r++) {
        float m = acc1[i][j][r], g = acc2[i][j][r];
        float h = (m / (1.f + __expf(-m))) * g;  // silu(m)*g
        int row = bm + wm + i * 16 + quad * 4 + r;
        int col = bn + wn + j * 16 + l16;
        Hp[(size_t)row * F_ + col] = f2bf(h);
      }
}

// ---------------- GEMM3: out = H @ W3 ----------------
// H: [G,F] bf16; W3t: [D,F] bf16 (k-contig); out: [G,D] fp32
// tile BM=128 BN=128 BK=32, 4 waves 2x2, 64x64 each. XCD patch = 4bm x 4bn.
__global__ __launch_bounds__(256) void k_mlp2(const u16* __restrict__ H,
                                              const u16* __restrict__ W3t,
                                              float* __restrict__ O) {
  __shared__ __align__(16) u16 As[128 * 32];  // 8KB
  __shared__ __align__(16) u16 Bs[128 * 32];  // 8KB
  // decode: 1024 blocks -> (e, bm-tile 0..15, bn-tile 0..7)
  const int l = blockIdx.x;
  const int xcd = l & 7, s = l >> 3;
  const int wp = s & 15, pl = s >> 4;
  const int pg = pl * 8 + xcd;         // 0..63
  const int e = pg >> 3, pe = pg & 7;  // 8 patches/expert
  const int bm = ((pe >> 1) * 4 + (wp >> 2)) * 128;
  const int bn = ((pe & 1) * 4 + (wp & 3)) * 128;

  const u16* A = H   + (size_t)e * G_ * F_;
  const u16* B = W3t + (size_t)e * D_ * F_;
  float* C = O + (size_t)e * G_ * D_;
  const int tid = threadIdx.x, wave = tid >> 6, lane = tid & 63;
  const int wm = (wave >> 1) * 64, wn = (wave & 1) * 64;
  const int quad = lane >> 4, l16 = lane & 15;

  const int ea0 = wave * 512 + lane * 8;
  const int ra0 = ea0 >> 5, ra1 = ra0 + 64;
  const int qs0 = (ea0 >> 3) & 3;
  const int ca0 = (qs0 ^ ((ra0 >> 1) & 3)) << 3;
  const int fco = ((quad ^ ((l16 >> 1) & 3)) << 3);

  f32x4 acc[4][4];
#pragma unroll
  for (int i = 0; i < 4; i++)
#pragma unroll
    for (int j = 0; j < 4; j++) acc[i][j] = f32x4{0.f, 0.f, 0.f, 0.f};

  for (int k0 = 0; k0 < F_; k0 += 32) {
    gld_lds16(A + (size_t)(bm + ra0) * F_ + k0 + ca0, (char*)As + wave * 1024);
    gld_lds16(A + (size_t)(bm + ra1) * F_ + k0 + ca0, (char*)As + (wave + 4) * 1024);
    gld_lds16(B + (size_t)(bn + ra0) * F_ + k0 + ca0, (char*)Bs + wave * 1024);
    gld_lds16(B + (size_t)(bn + ra1) * F_ + k0 + ca0, (char*)Bs + (wave + 4) * 1024);
    __syncthreads();
    bf16x8 af[4], bf[4];
#pragma unroll
    for (int i = 0; i < 4; i++) {
      af[i] = *(const bf16x8*)(As + (wm + i * 16 + l16) * 32 + fco);
      bf[i] = *(const bf16x8*)(Bs + (wn + i * 16 + l16) * 32 + fco);
    }
#pragma unroll
    for (int i = 0; i < 4; i++)
#pragma unroll
      for (int j = 0; j < 4; j++)
        acc[i][j] = __builtin_amdgcn_mfma_f32_16x16x32_bf16(af[i], bf[j], acc[i][j], 0, 0, 0);
    __syncthreads();
  }
#pragma unroll
  for (int i = 0; i < 4; i++)
#pragma unroll
    for (int j = 0; j < 4; j++)
#pragma unroll
      for (int r = 0; r < 4; r++) {
        int row = bm + wm + i * 16 + quad * 4 + r;
        int col = bn + wn + j * 16 + l16;
        C[(size_t)row * D_ + col] = acc[i][j][r];
      }
}

extern "C" void kernel_launch(void* const* d_in, const int* in_sizes, int n_in,
                              void* d_out, int out_size, void* d_ws, size_t ws_size,
                              hipStream_t stream) {
  const float* x  = (const float*)d_in[0];  // [E*G, D]
  const float* w1 = (const float*)d_in[1];  // [E*D, F]
  const float* w2 = (const float*)d_in[2];  // [E*D, F]
  const float* w3 = (const float*)d_in[3];  // [E*F, D]
  float* out = (float*)d_out;               // [E*G, D] fp32
  char* ws = (char*)d_ws;

  // workspace layout (288MB total):
  //   Xb  [0,   32MB)  bf16 [E][G][D]     (dead after k_mlp1)
  //   W1t [32,  96MB)  bf16 [E][F][D]     (dead after k_mlp1)
  //   W2t [96, 160MB)  bf16 [E][F][D]     (dead after k_mlp1)
  //   Hb  [160,288MB)  bf16 [E][G][F]
  //   W3t [0,   64MB)  bf16 [E][D][F]     (written AFTER k_mlp1; aliases Xb/W1t)
  u16* Xb  = (u16*)(ws);
  u16* W1t = (u16*)(ws + (size_t)32 * 1024 * 1024);
  u16* W2t = (u16*)(ws + (size_t)96 * 1024 * 1024);
  u16* Hb  = (u16*)(ws + (size_t)160 * 1024 * 1024);
  u16* W3t = (u16*)(ws);

  // 1) X fp32->bf16
  k_cvt<<<dim3((E_ * G_ * D_ / 8 + 255) / 256), dim3(256), 0, stream>>>(
      x, Xb, E_ * G_ * D_ / 8);
  // 2) W1,W2: [D,F] -> [F,D] bf16
  k_tcvt<<<dim3(F_ / 64, D_ / 64, E_), dim3(256), 0, stream>>>(w1, W1t, D_, F_);
  k_tcvt<<<dim3(F_ / 64, D_ / 64, E_), dim3(256), 0, stream>>>(w2, W2t, D_, F_);
  // 3) hidden = silu(X@W1) * (X@W2)
  k_mlp1<<<dim3(8192), dim3(256), 0, stream>>>(Xb, W1t, W2t, Hb);
  // 4) W3: [F,D] -> [D,F] bf16 (into region freed by Xb/W1t)
  k_tcvt<<<dim3(D_ / 64, F_ / 64, E_), dim3(256), 0, stream>>>(w3, W3t, F_, D_);
  // 5) out = hidden @ W3
  k_mlp2<<<dim3(1024), dim3(256), 0, stream>>>(Hb, W3t, out);
}